// Round 4
// baseline (38.710 us; speedup 1.0000x reference)
//
#include <hip/hip_runtime.h>
#include <math.h>

#define HIDDEN 2048
#define IN_F 350
#define NBLK 256
#define NTHR 512

// ws layout: floats [0..2048) = h1 (published via sc1 stores);
//            byte offset 16384 = barrier counter (uint, memset to 0 pre-launch).

__device__ __forceinline__ float sigmoidf_(float v) { return 1.0f / (1.0f + expf(-v)); }

// One fused kernel: feat -> LSTM0 -> relaxed-atomic grid barrier -> LSTM1 -> fc.
// 256 blocks x 512 thr. Block b owns hidden units [8b, 8b+8) in BOTH layers.
// No acquire/release fences anywhere (they buffer_wbl2/inv on gfx950 = disaster);
// cross-XCD visibility via agent-scope relaxed (sc1) ops + s_waitcnt vmcnt(0).
__global__ __launch_bounds__(NTHR) void fused_forecaster(
    const float* __restrict__ x,
    const float* __restrict__ Wih0, const float* __restrict__ bih0, const float* __restrict__ bhh0,
    const float* __restrict__ Wih1, const float* __restrict__ bih1, const float* __restrict__ bhh1,
    const float* __restrict__ fcw,  const float* __restrict__ fcb,
    float* __restrict__ h1g, unsigned* __restrict__ cnt, float* __restrict__ out)
{
    __shared__ float feat[IN_F];
    __shared__ float sc[12];
    __shared__ float hmin[4], hmax[4];
    __shared__ float gd[24];        // phase-0 per-(unit,gate) dots
    __shared__ float part[8][3];    // phase-1 per-wave gate dots
    __shared__ float h1s[HIDDEN];
    __shared__ float h2s[8];

    const int tid  = threadIdx.x;
    const int wave = tid >> 6, lane = tid & 63;
    const int b    = blockIdx.x;

    // ---- feature prep: hand extrema in parallel (waves 0-3), sources (wave 4) ----
    if (wave < 4) {
        const int hand = wave >> 1, coord = wave & 1;   // (left/right) x (x/y)
        float v = (lane < 21) ? x[182 + 42 * hand + 2 * lane + coord] : 0.0f;
        float vmin = (lane < 21) ? v :  1e30f;
        float vmax = (lane < 21) ? v : -1e30f;
        #pragma unroll
        for (int off = 32; off; off >>= 1) {
            vmin = fminf(vmin, __shfl_down(vmin, off));
            vmax = fmaxf(vmax, __shfl_down(vmax, off));
        }
        if (lane == 0) { hmin[wave] = vmin; hmax[wave] = vmax; }
    }
    if (wave == 4 && lane < 8) {
        const int srcIdx[8] = {0, 1, 106, 107, 200, 201, 242, 243};
        sc[lane] = x[srcIdx[lane]];   // src_body, src_face, src_left, src_right
    }
    __syncthreads();
    if (tid == 0) {
        float wl = hmax[0] - hmin[0], hl = hmax[1] - hmin[1];
        float wr = hmax[2] - hmin[2], hr = hmax[3] - hmin[3];
        bool okl = (wl != 0.0f) && (hl != 0.0f);
        bool okr = (wr != 0.0f) && (hr != 0.0f);
        sc[8]  = okl ? wl : 1.0f;  sc[9]  = okl ? hl : 1.0f;
        sc[10] = okr ? wr : 1.0f;  sc[11] = okr ? hr : 1.0f;
    }
    __syncthreads();
    if (tid < 133) {
        const float sbx = sc[0], sby = sc[1], sfx = sc[2], sfy = sc[3];
        const float slx = sc[4], sly = sc[5], srx = sc[6], sry = sc[7];
        const float dlx = sc[8], dly = sc[9], drx = sc[10], dry = sc[11];
        const int k = tid;
        float vx = x[2*k], vy = x[2*k + 1];
        if (k < 17) {                 // body
            feat[2*k]   = vx - sbx;  feat[2*k+1] = vy - sby;
        } else if (k < 23) {          // feet
            feat[2*k]   = vx;        feat[2*k+1] = vy;
        } else if (k < 91) {          // face
            feat[2*k]   = vx - sfx;  feat[2*k+1] = vy - sfy;
        } else if (k < 112) {         // left hand + chin2l
            int j = k - 91;
            feat[182 + 2*j] = (vx - slx) / dlx;  feat[183 + 2*j] = (vy - sly) / dly;
            feat[266 + 2*j] = vx - sbx;          feat[267 + 2*j] = vy - sby;
        } else {                      // right hand + chin2r
            int j = k - 112;
            feat[224 + 2*j] = (vx - srx) / drx;  feat[225 + 2*j] = (vy - sry) / dry;
            feat[308 + 2*j] = vx - sbx;          feat[309 + 2*j] = vy - sby;
        }
    }
    __syncthreads();

    // ---- phase 0: LSTM layer 0 (h=c=0 => f dead, W_hh unused). wave w = unit 8b+w ----
    if (wave < 8) {
        const int u = b * 8 + wave;
        #pragma unroll
        for (int g = 0; g < 3; ++g) {
            const int grow = ((g == 0) ? 0 : (g == 1) ? 2 : 3) * HIDDEN + u;  // i,g,o rows
            const float* wr = Wih0 + (size_t)grow * IN_F;
            float acc = 0.0f;
            for (int i = lane; i < IN_F; i += 64) acc += wr[i] * feat[i];
            #pragma unroll
            for (int off = 32; off; off >>= 1) acc += __shfl_down(acc, off);
            if (lane == 0) gd[wave * 3 + g] = acc;
        }
    }
    __syncthreads();
    if (tid < 8) {
        const int j = b * 8 + tid;
        float gi = gd[tid*3+0] + bih0[j]            + bhh0[j];
        float gg = gd[tid*3+1] + bih0[2*HIDDEN + j] + bhh0[2*HIDDEN + j];
        float go = gd[tid*3+2] + bih0[3*HIDDEN + j] + bhh0[3*HIDDEN + j];
        float c = sigmoidf_(gi) * tanhf(gg);
        float h = sigmoidf_(go) * tanhf(c);
        // publish to LLC (sc1, relaxed -> no cache flush)
        __hip_atomic_store(&h1g[j], h, __ATOMIC_RELAXED, __HIP_MEMORY_SCOPE_AGENT);
    }
    if (tid == 0) {
        // seed out with bias PRE-barrier: visible before any block's post-barrier atomicAdd
        __hip_atomic_store(&out[b], fcb[b], __ATOMIC_RELAXED, __HIP_MEMORY_SCOPE_AGENT);
        if (b < IN_F - NBLK)
            __hip_atomic_store(&out[NBLK + b], fcb[NBLK + b], __ATOMIC_RELAXED, __HIP_MEMORY_SCOPE_AGENT);
    }
    if (wave == 0) {
        asm volatile("s_waitcnt vmcnt(0)" ::: "memory");   // h1 + seeds committed to LLC
        if (lane == 0) {
            __hip_atomic_fetch_add(cnt, 1u, __ATOMIC_RELAXED, __HIP_MEMORY_SCOPE_AGENT);
            while (__hip_atomic_load(cnt, __ATOMIC_RELAXED, __HIP_MEMORY_SCOPE_AGENT)
                   < (unsigned)gridDim.x) {
                __builtin_amdgcn_s_sleep(2);
            }
        }
    }
    __syncthreads();   // whole block released once lane 0 exits spin

    // ---- gather full h1 from LLC into LDS (sc1 loads, coalesced) ----
    for (int i = tid; i < HIDDEN; i += NTHR)
        h1s[i] = __hip_atomic_load(&h1g[i], __ATOMIC_RELAXED, __HIP_MEMORY_SCOPE_AGENT);
    __syncthreads();

    // ---- phase 1: LSTM layer 1 (h=c=0 again). wave w = unit 8b+w, K=2048, float4 ----
    {
        const int u = b * 8 + wave;
        const float4* h4 = (const float4*)h1s;
        const float4* w0 = (const float4*)Wih0;  // placeholder type; real bases below
        const float4* wi = (const float4*)(Wih1 + (size_t)u * HIDDEN);
        const float4* wg = (const float4*)(Wih1 + ((size_t)2 * HIDDEN + u) * HIDDEN);
        const float4* wo = (const float4*)(Wih1 + ((size_t)3 * HIDDEN + u) * HIDDEN);
        (void)w0;
        float a0 = 0.f, a1 = 0.f, a2 = 0.f;
        #pragma unroll
        for (int it = 0; it < 8; ++it) {
            const int idx = it * 64 + lane;
            float4 hv = h4[idx];
            float4 wa = wi[idx], wb = wg[idx], wc = wo[idx];
            a0 += wa.x*hv.x + wa.y*hv.y + wa.z*hv.z + wa.w*hv.w;
            a1 += wb.x*hv.x + wb.y*hv.y + wb.z*hv.z + wb.w*hv.w;
            a2 += wc.x*hv.x + wc.y*hv.y + wc.z*hv.z + wc.w*hv.w;
        }
        #pragma unroll
        for (int off = 32; off; off >>= 1) {
            a0 += __shfl_down(a0, off);
            a1 += __shfl_down(a1, off);
            a2 += __shfl_down(a2, off);
        }
        if (lane == 0) { part[wave][0] = a0; part[wave][1] = a1; part[wave][2] = a2; }
    }
    __syncthreads();
    if (tid < 8) {
        const int j = b * 8 + tid;
        float gi = part[tid][0] + bih1[j]            + bhh1[j];
        float gg = part[tid][1] + bih1[2*HIDDEN + j] + bhh1[2*HIDDEN + j];
        float go = part[tid][2] + bih1[3*HIDDEN + j] + bhh1[3*HIDDEN + j];
        float c = sigmoidf_(gi) * tanhf(gg);
        h2s[tid] = sigmoidf_(go) * tanhf(c);     // h2 stays in LDS
    }
    __syncthreads();

    // ---- fc partial: this block's 8 columns of fc_w against h2s, one atomicAdd/row ----
    if (tid < IN_F) {
        const float4* wr4 = (const float4*)(fcw + (size_t)tid * HIDDEN + b * 8);
        float4 wa = wr4[0], wb = wr4[1];
        float p = wa.x*h2s[0] + wa.y*h2s[1] + wa.z*h2s[2] + wa.w*h2s[3]
                + wb.x*h2s[4] + wb.y*h2s[5] + wb.z*h2s[6] + wb.w*h2s[7];
        atomicAdd(&out[tid], p);
    }
}

extern "C" void kernel_launch(void* const* d_in, const int* in_sizes, int n_in,
                              void* d_out, int out_size, void* d_ws, size_t ws_size,
                              hipStream_t stream) {
    const float* x     = (const float*)d_in[0];
    const float* W_ih0 = (const float*)d_in[1];
    // d_in[2] = W_hh0 : unused (h0 == 0)
    const float* b_ih0 = (const float*)d_in[3];
    const float* b_hh0 = (const float*)d_in[4];
    const float* W_ih1 = (const float*)d_in[5];
    // d_in[6] = W_hh1 : unused (h == 0 for cell 2 as well)
    const float* b_ih1 = (const float*)d_in[7];
    const float* b_hh1 = (const float*)d_in[8];
    const float* fc_w  = (const float*)d_in[9];
    const float* fc_b  = (const float*)d_in[10];

    float*    h1g = (float*)d_ws;                          // 2048 floats
    unsigned* cnt = (unsigned*)((char*)d_ws + 16384);      // barrier counter

    hipMemsetAsync(cnt, 0, sizeof(unsigned), stream);      // re-arm barrier (capture-safe)
    fused_forecaster<<<NBLK, NTHR, 0, stream>>>(
        x, W_ih0, b_ih0, b_hh0, W_ih1, b_ih1, b_hh1, fc_w, fc_b,
        h1g, cnt, (float*)d_out);
}

// Round 5
// 21.865 us; speedup vs baseline: 1.7704x; 1.7704x over previous
//
#include <hip/hip_runtime.h>
#include <math.h>

#define HIDDEN 2048
#define IN_F 350

__device__ __forceinline__ float sigmoidf_(float v) { return 1.0f / (1.0f + expf(-v)); }
__device__ __forceinline__ float dot4_(float4 a, float4 b) {
    return a.x*b.x + a.y*b.y + a.z*b.z + a.w*b.w;
}

// K1: feat + LSTM layer 0 (h=c=0 => f-gate dead, W_hh unused).
// 2048 blocks x 192 thr: block = hidden unit, wave = gate (i,g,o). K=350, float2.
// feat computed redundantly per block, fully parallel (no serial thread-0 chain).
__global__ __launch_bounds__(192) void k1_feat_lstm0(
    const float* __restrict__ x, const float* __restrict__ Wih,
    const float* __restrict__ bih, const float* __restrict__ bhh,
    float* __restrict__ h1)
{
    __shared__ __align__(16) float feat[IN_F];
    __shared__ float hx[84];     // l0,r0 hand coords, contiguous copy of x[182..265]
    __shared__ float sc[12];     // 4 source points (8) + dl/dr (4)
    __shared__ float ext[4];     // wl, hl, wr, hr
    __shared__ float gd[3];
    const int tid = threadIdx.x, wave = tid >> 6, lane = tid & 63;
    const int j = blockIdx.x;

    if (tid < 84) hx[tid] = x[182 + tid];
    else if (tid < 92) {
        int t = tid - 84;
        int p = t >> 1;                                   // 0..3: body,face,left,right
        int base = (p == 0) ? 0 : (p == 1) ? 106 : (p == 2) ? 200 : 242;
        sc[t] = x[base + (t & 1)];
    }
    __syncthreads();
    if (tid < 4) {                                        // extrema: (hand, coord)
        const int h = tid >> 1, c = tid & 1;
        float m = hx[h*42 + c], M = m;
        #pragma unroll
        for (int jj = 1; jj < 21; ++jj) {
            float v = hx[h*42 + 2*jj + c];
            m = fminf(m, v); M = fmaxf(M, v);
        }
        ext[tid] = M - m;
    }
    __syncthreads();
    if (tid < 4) {
        const int h = tid >> 1;
        bool ok = (ext[2*h] != 0.0f) && (ext[2*h + 1] != 0.0f);
        sc[8 + tid] = ok ? ext[tid] : 1.0f;
    }
    __syncthreads();
    if (tid < 133) {
        const float sbx = sc[0], sby = sc[1], sfx = sc[2], sfy = sc[3];
        const float slx = sc[4], sly = sc[5], srx = sc[6], sry = sc[7];
        const float dlx = sc[8], dly = sc[9], drx = sc[10], dry = sc[11];
        const int k = tid;
        float vx = x[2*k], vy = x[2*k + 1];
        if (k < 17) {                 // body
            feat[2*k]   = vx - sbx;  feat[2*k+1] = vy - sby;
        } else if (k < 23) {          // feet
            feat[2*k]   = vx;        feat[2*k+1] = vy;
        } else if (k < 91) {          // face
            feat[2*k]   = vx - sfx;  feat[2*k+1] = vy - sfy;
        } else if (k < 112) {         // left hand + chin2l
            int jj = k - 91;
            feat[182 + 2*jj] = (vx - slx) / dlx;  feat[183 + 2*jj] = (vy - sly) / dly;
            feat[266 + 2*jj] = vx - sbx;          feat[267 + 2*jj] = vy - sby;
        } else {                      // right hand + chin2r
            int jj = k - 112;
            feat[224 + 2*jj] = (vx - srx) / drx;  feat[225 + 2*jj] = (vy - sry) / dry;
            feat[308 + 2*jj] = vx - sbx;          feat[309 + 2*jj] = vy - sby;
        }
    }
    __syncthreads();

    // gate dot: row = {0,2,3}[wave]*H + j, 350 floats = 175 float2 (rows 8B-aligned)
    const int grow = ((wave == 0) ? 0 : (wave == 1) ? 2 : 3) * HIDDEN + j;
    const float2* wr = (const float2*)(Wih + (size_t)grow * IN_F);
    const float2* f2 = (const float2*)feat;
    const bool has2 = (128 + lane) < 175;
    float2 w0 = wr[lane];
    float2 w1 = wr[64 + lane];
    float2 w2 = has2 ? wr[128 + lane] : make_float2(0.f, 0.f);
    float2 f0 = f2[lane];
    float2 f1 = f2[64 + lane];
    float2 fx = has2 ? f2[128 + lane] : make_float2(0.f, 0.f);
    float acc = w0.x*f0.x + w0.y*f0.y + w1.x*f1.x + w1.y*f1.y + w2.x*fx.x + w2.y*fx.y;
    #pragma unroll
    for (int off = 32; off; off >>= 1) acc += __shfl_down(acc, off);
    if (lane == 0) gd[wave] = acc + bih[grow] + bhh[grow];
    __syncthreads();
    if (tid == 0) {
        float c = sigmoidf_(gd[0]) * tanhf(gd[1]);
        h1[j] = sigmoidf_(gd[2]) * tanhf(c);
    }
}

// K2: LSTM layer 1 (h=c=0 again). 2048 blocks x 192 thr, block=unit, wave=gate.
// K=2048: 8 float4/lane, ALL loads hoisted into registers for deep MLP-stream ILP.
// h1 is 8 KB -> L1-resident; its global re-reads cost ~nothing.
__global__ __launch_bounds__(192) void k2_lstm1(
    const float* __restrict__ Wih, const float* __restrict__ bih,
    const float* __restrict__ bhh, const float* __restrict__ h1,
    float* __restrict__ h2)
{
    __shared__ float gd[3];
    const int tid = threadIdx.x, wave = tid >> 6, lane = tid & 63;
    const int j = blockIdx.x;
    const int grow = ((wave == 0) ? 0 : (wave == 1) ? 2 : 3) * HIDDEN + j;
    const float4* wr = (const float4*)(Wih + (size_t)grow * HIDDEN);
    const float4* h4 = (const float4*)h1;

    float4 wv0 = wr[lane];
    float4 wv1 = wr[ 64 + lane];
    float4 wv2 = wr[128 + lane];
    float4 wv3 = wr[192 + lane];
    float4 wv4 = wr[256 + lane];
    float4 wv5 = wr[320 + lane];
    float4 wv6 = wr[384 + lane];
    float4 wv7 = wr[448 + lane];
    float4 hv0 = h4[lane];
    float4 hv1 = h4[ 64 + lane];
    float4 hv2 = h4[128 + lane];
    float4 hv3 = h4[192 + lane];
    float4 hv4 = h4[256 + lane];
    float4 hv5 = h4[320 + lane];
    float4 hv6 = h4[384 + lane];
    float4 hv7 = h4[448 + lane];

    float acc = dot4_(wv0, hv0) + dot4_(wv1, hv1) + dot4_(wv2, hv2) + dot4_(wv3, hv3)
              + dot4_(wv4, hv4) + dot4_(wv5, hv5) + dot4_(wv6, hv6) + dot4_(wv7, hv7);
    #pragma unroll
    for (int off = 32; off; off >>= 1) acc += __shfl_down(acc, off);
    if (lane == 0) gd[wave] = acc + bih[grow] + bhh[grow];
    __syncthreads();
    if (tid == 0) {
        float c = sigmoidf_(gd[0]) * tanhf(gd[1]);
        h2[j] = sigmoidf_(gd[2]) * tanhf(c);
    }
}

// K3: out[r] = fc_w[r,:] . h2 + fc_b[r]. 350 blocks x 256 thr (4 waves, K-split).
__global__ __launch_bounds__(256) void k3_fc(
    const float* __restrict__ h2, const float* __restrict__ W,
    const float* __restrict__ b, float* __restrict__ out)
{
    __shared__ float part[4];
    const int tid = threadIdx.x, wave = tid >> 6, lane = tid & 63;
    const int r = blockIdx.x;
    const float4* wr = (const float4*)(W + (size_t)r * HIDDEN);
    const float4* h4 = (const float4*)h2;
    const int base = wave * 128;              // 512 float4 / 4 waves
    float4 w0 = wr[base + lane], w1 = wr[base + 64 + lane];
    float4 v0 = h4[base + lane], v1 = h4[base + 64 + lane];
    float acc = dot4_(w0, v0) + dot4_(w1, v1);
    #pragma unroll
    for (int off = 32; off; off >>= 1) acc += __shfl_down(acc, off);
    if (lane == 0) part[wave] = acc;
    __syncthreads();
    if (tid == 0) out[r] = part[0] + part[1] + part[2] + part[3] + b[r];
}

extern "C" void kernel_launch(void* const* d_in, const int* in_sizes, int n_in,
                              void* d_out, int out_size, void* d_ws, size_t ws_size,
                              hipStream_t stream) {
    const float* x     = (const float*)d_in[0];
    const float* W_ih0 = (const float*)d_in[1];
    // d_in[2] = W_hh0 : unused (h0 == 0)
    const float* b_ih0 = (const float*)d_in[3];
    const float* b_hh0 = (const float*)d_in[4];
    const float* W_ih1 = (const float*)d_in[5];
    // d_in[6] = W_hh1 : unused (h == 0 for cell 2 as well)
    const float* b_ih1 = (const float*)d_in[7];
    const float* b_hh1 = (const float*)d_in[8];
    const float* fc_w  = (const float*)d_in[9];
    const float* fc_b  = (const float*)d_in[10];

    float* h1 = (float*)d_ws;            // 2048 floats
    float* h2 = (float*)d_ws + HIDDEN;   // 2048 floats

    k1_feat_lstm0<<<HIDDEN, 192, 0, stream>>>(x, W_ih0, b_ih0, b_hh0, h1);
    k2_lstm1<<<HIDDEN, 192, 0, stream>>>(W_ih1, b_ih1, b_hh1, h1, h2);
    k3_fc<<<IN_F, 256, 0, stream>>>(h2, fc_w, fc_b, (float*)d_out);
}